// Round 5
// baseline (53.194 us; speedup 1.0000x reference)
//
#include <hip/hip_runtime.h>
#include <hip/hip_bf16.h>

#define M_ROWS 8192
#define HALF_N 4096
#define D 128
#define INV_T 2.0f   // 1 / temperature(0.5)
#define NTC 4        // j-tiles per chunk
#define NPANEL 64    // 8192 / 128 row panels

typedef __attribute__((ext_vector_type(4))) float f32x4;
typedef __attribute__((ext_vector_type(8))) short bf16x8;
typedef unsigned int u32;
typedef __attribute__((ext_vector_type(4))) u32 u32x4;

// ---------------------------------------------------------------------------
// Kernel A: L2-normalize rows (fp32 in, bf16 out), zero rowsum accumulator.
// ---------------------------------------------------------------------------
__global__ __launch_bounds__(256) void k_normalize(
    const float* __restrict__ zi, const float* __restrict__ zj,
    __hip_bfloat16* __restrict__ zb, float* __restrict__ rowsum)
{
    int t = blockIdx.x * 256 + threadIdx.x;
    if (t < M_ROWS) rowsum[t] = 0.0f;   // re-init every launch (ws not re-poisoned)

    int row  = t >> 6;
    int lane = t & 63;
    const float* src = (row < HALF_N) ? (zi + (size_t)row * D)
                                      : (zj + (size_t)(row - HALF_N) * D);
    float2 v = *(const float2*)(src + lane * 2);
    float ss = v.x * v.x + v.y * v.y;
    #pragma unroll
    for (int o = 32; o >= 1; o >>= 1) ss += __shfl_xor(ss, o);
    float scale = 1.0f / fmaxf(sqrtf(ss), 1e-12f);

    __hip_bfloat162 o2;
    o2.x = __float2bfloat16(v.x * scale);
    o2.y = __float2bfloat16(v.y * scale);
    *(__hip_bfloat162*)(zb + (size_t)row * D + lane * 2) = o2;
}

// ---------------------------------------------------------------------------
// Kernel B (symmetric): block (pi, c) computes tiles (pi, pj) for
// pj in [pi+4c, pi+4c+3] ∩ [pi, 63] — upper triangle only, each sim tile
// computed ONCE. Row-sums for panel pi accumulate in registers across the
// chunk (128 atomics per block at the end). Each off-diagonal tile also
// yields panel-pj row-sums via column reduction: in-lane sum over (m,r),
// shfl over lg, LDS combine of 4 waves, 128 atomics per tile.
// A-tile in registers; B-tile in one 32KB LDS buffer, reg-staged prefetch.
// ---------------------------------------------------------------------------
__global__ __launch_bounds__(256, 3) void k_simsum(
    const __hip_bfloat16* __restrict__ zb, float* __restrict__ rowsum)
{
    __shared__ char  sB[32768];          // one 128x128 bf16 B-tile
    __shared__ float colLDS[4][128];     // per-wave column partials

    const int pi = blockIdx.y;                 // row panel
    const int j0 = pi + blockIdx.x * NTC;      // first col panel of chunk
    if (j0 >= NPANEL) return;
    const int ntiles = min(NTC, NPANEL - j0);

    const int ibase = pi * 128;
    const int tid   = threadIdx.x;
    const int wv    = tid >> 6, lane = tid & 63;
    const int lr    = lane & 15, lg = lane >> 4;
    const int rbase = wv * 32;

    // A fragments: 32 rows x K=128 per wave, in 32 VGPRs (from L2).
    bf16x8 a[2][4];
    #pragma unroll
    for (int m = 0; m < 2; ++m)
        #pragma unroll
        for (int ks = 0; ks < 4; ++ks) {
            int row = ibase + rbase + m * 16 + lr;
            a[m][ks] = *(const bf16x8*)(zb + (size_t)row * D + (ks * 4 + lg) * 8);
        }

    // Reg-staged B tile: linear coalesced loads, swizzled ds_write.
    u32x4 breg[8];
    auto load_tile = [&](int pj) {
        #pragma unroll
        for (int i = 0; i < 8; ++i) {
            int row = (wv * 8 + i) * 4 + lg;
            breg[i] = *(const u32x4*)(zb + (size_t)(pj * 128 + row) * D + lr * 8);
        }
    };
    auto write_tile = [&]() {
        #pragma unroll
        for (int i = 0; i < 8; ++i) {
            int row = (wv * 8 + i) * 4 + lg;
            *(u32x4*)(sB + row * 256 + ((lr ^ (row & 7)) << 4)) = breg[i];
        }
    };

    float eacc[2][4] = {{0.f, 0.f, 0.f, 0.f}, {0.f, 0.f, 0.f, 0.f}};

    load_tile(j0);
    write_tile();
    __syncthreads();

    for (int t = 0; t < ntiles; ++t) {
        const int pj = j0 + t;
        if (t + 1 < ntiles) load_tile(pj + 1);   // prefetch under compute

        f32x4 acc[2][8];
        #pragma unroll
        for (int m = 0; m < 2; ++m)
            #pragma unroll
            for (int n = 0; n < 8; ++n) acc[m][n] = (f32x4){0.f, 0.f, 0.f, 0.f};

        #pragma unroll
        for (int ks = 0; ks < 4; ++ks) {
            #pragma unroll
            for (int n = 0; n < 8; ++n) {
                int rowB = n * 16 + lr;
                bf16x8 b = *(const bf16x8*)(sB + rowB * 256 +
                            ((((ks << 2) + lg) ^ (lr & 7)) << 4));
                acc[0][n] = __builtin_amdgcn_mfma_f32_16x16x32_bf16(a[0][ks], b, acc[0][n], 0, 0, 0);
                acc[1][n] = __builtin_amdgcn_mfma_f32_16x16x32_bf16(a[1][ks], b, acc[1][n], 0, 0, 0);
            }
        }

        // exp once per element; feed row accumulator AND column partials.
        float cs[8] = {0.f, 0.f, 0.f, 0.f, 0.f, 0.f, 0.f, 0.f};
        #pragma unroll
        for (int m = 0; m < 2; ++m)
            #pragma unroll
            for (int n = 0; n < 8; ++n)
                #pragma unroll
                for (int r = 0; r < 4; ++r) {
                    float e = __expf(INV_T * acc[m][n][r]);
                    eacc[m][r] += e;
                    cs[n]      += e;
                }

        // Column reduce: cs[n] holds 8 rows (lg*4+r, both m) -> sum over lg.
        #pragma unroll
        for (int n = 0; n < 8; ++n) {
            cs[n] += __shfl_xor(cs[n], 16);
            cs[n] += __shfl_xor(cs[n], 32);
        }
        if (lg == 0) {
            #pragma unroll
            for (int n = 0; n < 8; ++n) colLDS[wv][n * 16 + lr] = cs[n];
        }

        __syncthreads();                 // B reads + colLDS writes complete
        if (t + 1 < ntiles) write_tile();
        if (pj != pi && tid < 128) {     // diag tile: row-sums already cover it
            float cv = colLDS[0][tid] + colLDS[1][tid] +
                       colLDS[2][tid] + colLDS[3][tid];
            atomicAdd(&rowsum[pj * 128 + tid], cv);
        }
        __syncthreads();                 // B written + colLDS consumable again
    }

    // Row epilogue: reduce over the 16 col-lanes, one atomic per row.
    #pragma unroll
    for (int m = 0; m < 2; ++m)
        #pragma unroll
        for (int r = 0; r < 4; ++r) {
            float e = eacc[m][r];
            e += __shfl_xor(e, 1);
            e += __shfl_xor(e, 2);
            e += __shfl_xor(e, 4);
            e += __shfl_xor(e, 8);
            if (lr == 0)
                atomicAdd(&rowsum[ibase + rbase + m * 16 + lg * 4 + r], e);
        }
}

// ---------------------------------------------------------------------------
// Kernel C: per row, recompute self-dot and positive-pair dot (fp32 from
// bf16), lse = log(rowsum - exp(2*self) + exp(2*pos)), write lse - pos.
// ---------------------------------------------------------------------------
__global__ __launch_bounds__(256) void k_rowloss(
    const __hip_bfloat16* __restrict__ zb, const float* __restrict__ rowsum,
    float* __restrict__ rowloss)
{
    int t = blockIdx.x * 256 + threadIdx.x;
    int row = t >> 6, lane = t & 63;
    int pair = row ^ HALF_N;

    __hip_bfloat162 av = *(const __hip_bfloat162*)(zb + (size_t)row  * D + lane * 2);
    __hip_bfloat162 bv = *(const __hip_bfloat162*)(zb + (size_t)pair * D + lane * 2);
    float ax = __bfloat162float(av.x), ay = __bfloat162float(av.y);
    float bx = __bfloat162float(bv.x), by = __bfloat162float(bv.y);
    float sd = ax * ax + ay * ay;
    float pd = ax * bx + ay * by;
    #pragma unroll
    for (int o = 32; o >= 1; o >>= 1) {
        sd += __shfl_xor(sd, o);
        pd += __shfl_xor(pd, o);
    }
    if (lane == 0) {
        float rs  = rowsum[row];
        float val = rs - __expf(INV_T * sd) + __expf(INV_T * pd);
        rowloss[row] = logf(val) - INV_T * pd;
    }
}

// ---------------------------------------------------------------------------
// Kernel D: single-block tree reduction of rowloss[8192] -> mean.
// ---------------------------------------------------------------------------
__global__ __launch_bounds__(1024) void k_reduce(
    const float* __restrict__ rowloss, float* __restrict__ out)
{
    __shared__ float sm[16];
    int tid = threadIdx.x;
    float s = 0.f;
    #pragma unroll
    for (int i = 0; i < M_ROWS / 1024; ++i) s += rowloss[i * 1024 + tid];
    #pragma unroll
    for (int o = 32; o >= 1; o >>= 1) s += __shfl_xor(s, o);
    if ((tid & 63) == 0) sm[tid >> 6] = s;
    __syncthreads();
    if (tid == 0) {
        float tot = 0.f;
        #pragma unroll
        for (int w = 0; w < 16; ++w) tot += sm[w];
        out[0] = tot * (1.0f / (float)M_ROWS);
    }
}

// ---------------------------------------------------------------------------
extern "C" void kernel_launch(void* const* d_in, const int* in_sizes, int n_in,
                              void* d_out, int out_size, void* d_ws, size_t ws_size,
                              hipStream_t stream)
{
    const float* zi = (const float*)d_in[0];
    const float* zj = (const float*)d_in[1];

    float* rowsum  = (float*)d_ws;                               // 8192 f32
    float* rowloss = rowsum + M_ROWS;                            // 8192 f32
    __hip_bfloat16* zb = (__hip_bfloat16*)((char*)d_ws + 65536); // 8192x128 bf16

    k_normalize<<<dim3(M_ROWS * 64 / 256), 256, 0, stream>>>(zi, zj, zb, rowsum);
    k_simsum<<<dim3(16, 64), dim3(256), 0, stream>>>(zb, rowsum);
    k_rowloss<<<dim3(M_ROWS * 64 / 256), 256, 0, stream>>>(zb, rowsum, rowloss);
    k_reduce<<<dim3(1), dim3(1024), 0, stream>>>(rowloss, (float*)d_out);
}

// Round 6
// 49.734 us; speedup vs baseline: 1.0696x; 1.0696x over previous
//
#include <hip/hip_runtime.h>
#include <hip/hip_bf16.h>

#define M_ROWS 8192
#define HALF_N 4096
#define D 128
#define NPANEL 64        // 8192 / 128 panels
#define NTC 4            // j-tiles per chunk block
#define NBLK 544         // sum_{pi} ceil((64-pi)/4)
#define E2C 2.8853900817779268f   // INV_T(=2) * log2(e)

typedef __attribute__((ext_vector_type(4))) float f32x4;
typedef __attribute__((ext_vector_type(8))) short bf16x8;
typedef unsigned int u32;
typedef __attribute__((ext_vector_type(4))) u32 u32x4;

// ---------------------------------------------------------------------------
// Kernel A: L2-normalize rows (fp32 in, bf16 out), zero rowsum accumulator.
// ---------------------------------------------------------------------------
__global__ __launch_bounds__(256) void k_normalize(
    const float* __restrict__ zi, const float* __restrict__ zj,
    __hip_bfloat16* __restrict__ zb, float* __restrict__ rowsum)
{
    int t = blockIdx.x * 256 + threadIdx.x;
    if (t < M_ROWS) rowsum[t] = 0.0f;   // re-init every launch (ws not re-poisoned)

    int row  = t >> 6;
    int lane = t & 63;
    const float* src = (row < HALF_N) ? (zi + (size_t)row * D)
                                      : (zj + (size_t)(row - HALF_N) * D);
    float2 v = *(const float2*)(src + lane * 2);
    float ss = v.x * v.x + v.y * v.y;
    #pragma unroll
    for (int o = 32; o >= 1; o >>= 1) ss += __shfl_xor(ss, o);
    float scale = 1.0f / fmaxf(sqrtf(ss), 1e-12f);

    __hip_bfloat162 o2;
    o2.x = __float2bfloat16(v.x * scale);
    o2.y = __float2bfloat16(v.y * scale);
    *(__hip_bfloat162*)(zb + (size_t)row * D + lane * 2) = o2;
}

// ---------------------------------------------------------------------------
// Kernel B (symmetric, decoupled): block covers row panel pi x up to 4 col
// panels pj in [pi+4c, pi+4c+3] ∩ [pi,63] — upper triangle, each tile once.
// Row-side sums accumulate in registers; 128 fire-and-forget atomics at end.
// Col-side sums (pj > pi) are per-wave shfl-reduced and stored NON-atomically
// to private scratch colpart[pj][col][pi*4+wv]; k_rowloss folds them in.
// Double-buffered LDS B-tile, reg prefetch 2 ahead, ONE barrier per tile.
// ---------------------------------------------------------------------------
__global__ __launch_bounds__(256, 2) void k_simsum(
    const __hip_bfloat16* __restrict__ zb, float* __restrict__ rowsum,
    float* __restrict__ colpart)
{
    __shared__ char sB[2][32768];

    // Flattened upper-triangle chunk index -> (pi, chunk)
    int b = blockIdx.x, pi = 0;
    for (;;) { int cnt = (67 - pi) >> 2; if (b < cnt) break; b -= cnt; ++pi; }
    const int j0     = pi + (b << 2);
    const int ntiles = min(NTC, NPANEL - j0);

    const int ibase = pi * 128;
    const int tid   = threadIdx.x;
    const int wv    = tid >> 6, lane = tid & 63;
    const int lr    = lane & 15, lg = lane >> 4;
    const int rbase = wv * 32;

    // A fragments: 32 rows x K=128 per wave, in 32 VGPRs (from L2).
    bf16x8 a[2][4];
    #pragma unroll
    for (int m = 0; m < 2; ++m)
        #pragma unroll
        for (int ks = 0; ks < 4; ++ks) {
            int row = ibase + rbase + m * 16 + lr;
            a[m][ks] = *(const bf16x8*)(zb + (size_t)row * D + (ks * 4 + lg) * 8);
        }

    // Reg-staged B tile: linear coalesced loads, swizzled ds_write.
    u32x4 breg[8];
    auto load_tile = [&](int pj) {
        #pragma unroll
        for (int i = 0; i < 8; ++i) {
            int row = (wv * 8 + i) * 4 + lg;
            breg[i] = *(const u32x4*)(zb + (size_t)(pj * 128 + row) * D + lr * 8);
        }
    };
    auto write_tile = [&](char* buf) {
        #pragma unroll
        for (int i = 0; i < 8; ++i) {
            int row = (wv * 8 + i) * 4 + lg;
            *(u32x4*)(buf + row * 256 + ((lr ^ (row & 7)) << 4)) = breg[i];
        }
    };

    float eacc[2][4] = {{0.f, 0.f, 0.f, 0.f}, {0.f, 0.f, 0.f, 0.f}};

    load_tile(j0);
    write_tile(sB[0]);
    if (ntiles > 1) load_tile(j0 + 1);
    __syncthreads();

    for (int t = 0; t < ntiles; ++t) {
        const int pj = j0 + t;
        // Fill the other buffer for t+1 (its last readers finished at t-1's
        // barrier), then prefetch t+2 into regs.
        if (t + 1 < ntiles) write_tile(sB[(t + 1) & 1]);
        if (t + 2 < ntiles) load_tile(j0 + t + 2);

        const char* cur = sB[t & 1];
        f32x4 acc[2][8];
        #pragma unroll
        for (int m = 0; m < 2; ++m)
            #pragma unroll
            for (int n = 0; n < 8; ++n) acc[m][n] = (f32x4){0.f, 0.f, 0.f, 0.f};

        #pragma unroll
        for (int ks = 0; ks < 4; ++ks) {
            #pragma unroll
            for (int n = 0; n < 8; ++n) {
                int rowB = n * 16 + lr;
                bf16x8 bfr = *(const bf16x8*)(cur + rowB * 256 +
                              ((((ks << 2) + lg) ^ (lr & 7)) << 4));
                acc[0][n] = __builtin_amdgcn_mfma_f32_16x16x32_bf16(a[0][ks], bfr, acc[0][n], 0, 0, 0);
                acc[1][n] = __builtin_amdgcn_mfma_f32_16x16x32_bf16(a[1][ks], bfr, acc[1][n], 0, 0, 0);
            }
        }

        // exp once per element; feed row accumulator AND column partials.
        float cs[8] = {0.f, 0.f, 0.f, 0.f, 0.f, 0.f, 0.f, 0.f};
        #pragma unroll
        for (int m = 0; m < 2; ++m)
            #pragma unroll
            for (int n = 0; n < 8; ++n)
                #pragma unroll
                for (int r = 0; r < 4; ++r) {
                    float e = exp2f(acc[m][n][r] * E2C);
                    eacc[m][r] += e;
                    cs[n]      += e;
                }

        // Column partials: sum over lg -> full 32-row-of-wave col sums; store
        // to private scratch (no atomics, no barrier dependency).
        if (pj != pi) {
            #pragma unroll
            for (int n = 0; n < 8; ++n) {
                cs[n] += __shfl_xor(cs[n], 16);
                cs[n] += __shfl_xor(cs[n], 32);
            }
            if (lg == 0) {
                float* dst = colpart + (size_t)pj * 32768 + (pi * 4 + wv);
                #pragma unroll
                for (int n = 0; n < 8; ++n)
                    dst[(n * 16 + lr) * 256] = cs[n];
            }
        }

        __syncthreads();   // buf[t&1] reads done; buf[(t+1)&1] writes visible
    }

    // Row epilogue: reduce over the 16 col-lanes, fire-and-forget atomics.
    #pragma unroll
    for (int m = 0; m < 2; ++m)
        #pragma unroll
        for (int r = 0; r < 4; ++r) {
            float e = eacc[m][r];
            e += __shfl_xor(e, 1);
            e += __shfl_xor(e, 2);
            e += __shfl_xor(e, 4);
            e += __shfl_xor(e, 8);
            if (lr == 0)
                atomicAdd(&rowsum[ibase + rbase + m * 16 + lg * 4 + r], e);
        }
}

// ---------------------------------------------------------------------------
// Kernel C: per row, fold in column-side partials (coalesced reads from
// colpart[pj][col][k], k = pi*4+wv < 4*pj), recompute self/pair dots,
// lse = log(total - exp(2*self) + exp(2*pos)), write lse - pos.
// ---------------------------------------------------------------------------
__global__ __launch_bounds__(256) void k_rowloss(
    const __hip_bfloat16* __restrict__ zb, const float* __restrict__ rowsum,
    const float* __restrict__ colpart, float* __restrict__ rowloss)
{
    int t = blockIdx.x * 256 + threadIdx.x;
    int row = t >> 6, lane = t & 63;
    int pair = row ^ HALF_N;
    int pj = row >> 7, cl = row & 127;

    // Column-side contributions for this row: 4*pj consecutive floats.
    const float* cp = colpart + (size_t)pj * 32768 + cl * 256;
    float colc = 0.f;
    for (int k = lane; k < 4 * pj; k += 64) colc += cp[k];

    __hip_bfloat162 av = *(const __hip_bfloat162*)(zb + (size_t)row  * D + lane * 2);
    __hip_bfloat162 bv = *(const __hip_bfloat162*)(zb + (size_t)pair * D + lane * 2);
    float ax = __bfloat162float(av.x), ay = __bfloat162float(av.y);
    float bx = __bfloat162float(bv.x), by = __bfloat162float(bv.y);
    float sd = ax * ax + ay * ay;
    float pd = ax * bx + ay * by;
    #pragma unroll
    for (int o = 32; o >= 1; o >>= 1) {
        sd   += __shfl_xor(sd, o);
        pd   += __shfl_xor(pd, o);
        colc += __shfl_xor(colc, o);
    }
    if (lane == 0) {
        float rs  = rowsum[row] + colc;
        float val = rs - exp2f(sd * E2C) + exp2f(pd * E2C);
        rowloss[row] = logf(val) - 2.0f * pd;
    }
}

// ---------------------------------------------------------------------------
// Kernel D: single-block tree reduction of rowloss[8192] -> mean.
// ---------------------------------------------------------------------------
__global__ __launch_bounds__(1024) void k_reduce(
    const float* __restrict__ rowloss, float* __restrict__ out)
{
    __shared__ float sm[16];
    int tid = threadIdx.x;
    float s = 0.f;
    #pragma unroll
    for (int i = 0; i < M_ROWS / 1024; ++i) s += rowloss[i * 1024 + tid];
    #pragma unroll
    for (int o = 32; o >= 1; o >>= 1) s += __shfl_xor(s, o);
    if ((tid & 63) == 0) sm[tid >> 6] = s;
    __syncthreads();
    if (tid == 0) {
        float tot = 0.f;
        #pragma unroll
        for (int w = 0; w < 16; ++w) tot += sm[w];
        out[0] = tot * (1.0f / (float)M_ROWS);
    }
}

// ---------------------------------------------------------------------------
extern "C" void kernel_launch(void* const* d_in, const int* in_sizes, int n_in,
                              void* d_out, int out_size, void* d_ws, size_t ws_size,
                              hipStream_t stream)
{
    const float* zi = (const float*)d_in[0];
    const float* zj = (const float*)d_in[1];

    float* rowsum  = (float*)d_ws;                               // 8192 f32
    float* rowloss = rowsum + M_ROWS;                            // 8192 f32
    __hip_bfloat16* zb = (__hip_bfloat16*)((char*)d_ws + 65536); // 8192x128 bf16
    float* colpart = (float*)((char*)d_ws + 65536 + M_ROWS * D * 2); // 64*128*256 f32 = 8 MB

    k_normalize<<<dim3(M_ROWS * 64 / 256), 256, 0, stream>>>(zi, zj, zb, rowsum);
    k_simsum<<<dim3(NBLK), dim3(256), 0, stream>>>(zb, rowsum, colpart);
    k_rowloss<<<dim3(M_ROWS * 64 / 256), 256, 0, stream>>>(zb, rowsum, colpart, rowloss);
    k_reduce<<<dim3(1), dim3(1024), 0, stream>>>(rowloss, (float*)d_out);
}